// Round 14
// baseline (303.680 us; speedup 1.0000x reference)
//
#include <hip/hip_runtime.h>
#include <math.h>

typedef _Float16 f16x8 __attribute__((ext_vector_type(8)));
typedef unsigned short us8 __attribute__((ext_vector_type(8)));
typedef float f32x4 __attribute__((ext_vector_type(4)));

__device__ inline unsigned short f2h(float f) {
    _Float16 h = (_Float16)f;
    return *(unsigned short*)&h;
}
__device__ inline float h2f(unsigned short u) {
    _Float16 h = *(_Float16*)&u;
    return (float)h;
}

// fragment-packed offset (in halves) for element (row, col) in a buffer with KT cols
__device__ __forceinline__ size_t pkoff(int row, int col, int KT) {
    return ((size_t)(row >> 4) * (KT >> 5) + (col >> 5)) * 512
         + (size_t)(((col >> 3) & 3) * 128 + ((row & 15) << 3) + (col & 7));
}

// ============================================================ bucketed CSR build
#define ECH 4096

__global__ __launch_bounds__(256)
void bucket_hist(const int* __restrict__ edst, int* __restrict__ bcnt, int E, int NB) {
    __shared__ int h[512];
    int tid = threadIdx.x;
    for (int i = tid; i < NB; i += 256) h[i] = 0;
    __syncthreads();
    int c0 = blockIdx.x * ECH, c1 = min(c0 + ECH, E);
    for (int e = c0 + tid; e < c1; e += 256) atomicAdd(&h[edst[e] >> 7], 1);
    __syncthreads();
    for (int i = tid; i < NB; i += 256) if (h[i]) atomicAdd(&bcnt[i], h[i]);
}

__global__ __launch_bounds__(512)
void bucket_scan(const int* __restrict__ bcnt, int* __restrict__ bbase,
                 int* __restrict__ bcur, int* __restrict__ rowstart, int NB, int n) {
    __shared__ int ws[8];
    int tid = threadIdx.x, lane = tid & 63, wid = tid >> 6;
    int v = (tid < NB) ? bcnt[tid] : 0;
    int x = v;
    for (int d = 1; d < 64; d <<= 1) { int y = __shfl_up(x, d); if (lane >= d) x += y; }
    if (lane == 63) ws[wid] = x;
    __syncthreads();
    int off = 0;
    for (int w = 0; w < wid; w++) off += ws[w];
    int excl = x - v + off;
    if (tid < NB) { bbase[tid] = excl; bcur[tid] = excl; }
    if (tid == 0) {
        int tot = 0;
        for (int w = 0; w < 8; w++) tot += ws[w];
        bbase[NB] = tot;
        rowstart[n] = tot;
    }
}

__global__ __launch_bounds__(256)
void bucket_scatter(const int* __restrict__ esrc_in, const int* __restrict__ edst_in,
                    int* __restrict__ bcur, unsigned* __restrict__ bedge, int E, int NB) {
    __shared__ int h[512];
    __shared__ int rb[512];
    int tid = threadIdx.x;
    for (int i = tid; i < NB; i += 256) h[i] = 0;
    __syncthreads();
    int c0 = blockIdx.x * ECH, c1 = min(c0 + ECH, E);
    for (int e = c0 + tid; e < c1; e += 256) atomicAdd(&h[edst_in[e] >> 7], 1);
    __syncthreads();
    for (int i = tid; i < NB; i += 256) {
        rb[i] = h[i] ? atomicAdd(&bcur[i], h[i]) : 0;
        h[i] = 0;   // reuse as local cursor
    }
    __syncthreads();
    for (int e = c0 + tid; e < c1; e += 256) {
        int dst = edst_in[e], src = esrc_in[e];
        int b = dst >> 7;
        int o = atomicAdd(&h[b], 1);
        bedge[rb[b] + o] = (unsigned)src | ((unsigned)(dst & 127) << 16);
    }
}

__global__ __launch_bounds__(256)
void node_csr(const unsigned* __restrict__ bedge, const int* __restrict__ bbase,
              int* __restrict__ rowstart, float* __restrict__ degf,
              unsigned short* __restrict__ esrc, int n) {
    __shared__ int cnt[128];
    __shared__ int cur[128];
    __shared__ int ws4[4];
    int b = blockIdx.x, tid = threadIdx.x;
    int lane = tid & 63, wid = tid >> 6;
    int n0 = b << 7;
    int eb0 = bbase[b], eb1 = bbase[b + 1];
    if (tid < 128) cnt[tid] = 0;
    __syncthreads();
    for (int e = eb0 + tid; e < eb1; e += 256) atomicAdd(&cnt[(bedge[e] >> 16) & 127], 1);
    __syncthreads();
    int v = (tid < 128) ? cnt[tid] : 0;
    int x = v;
    for (int d = 1; d < 64; d <<= 1) { int y = __shfl_up(x, d); if (lane >= d) x += y; }
    if (lane == 63) ws4[wid] = x;
    __syncthreads();
    int off = 0;
    for (int w = 0; w < wid; w++) off += ws4[w];
    int excl = x - v + off;
    if (tid < 128 && n0 + tid < n) {
        rowstart[n0 + tid] = eb0 + excl;
        cur[tid] = eb0 + excl;
        degf[n0 + tid] = (float)(v > 0 ? v : 1);
    }
    __syncthreads();
    for (int e = eb0 + tid; e < eb1; e += 256) {
        unsigned u = bedge[e];
        int p = atomicAdd(&cur[(u >> 16) & 127], 1);
        esrc[p] = (unsigned short)(u & 0xffffu);
    }
}

// ---------------------------------------------------------------- merged prep: zero bcnt, init pool, pack weights
__global__ __launch_bounds__(256)
void prep_k(int* __restrict__ bcnt, float* __restrict__ pmax, float* __restrict__ psum, int G,
            const float* __restrict__ ws0, const float* __restrict__ wn0, unsigned short* __restrict__ WP0,
            const float* __restrict__ ws1, const float* __restrict__ wn1, unsigned short* __restrict__ WP1,
            const float* __restrict__ ws2, const float* __restrict__ wn2, unsigned short* __restrict__ WP2,
            const float* __restrict__ ws3, const float* __restrict__ wn3, unsigned short* __restrict__ WP3) {
    int t = blockIdx.x * 256 + threadIdx.x;
    if (t < 512) bcnt[t] = 0;
    if (t < G * 256) { pmax[t] = -INFINITY; psum[t] = 0.f; }
    if (t < 8192) {
        int k = t >> 6, n = t & 63;
        float v = (k < 64) ? ws0[k * 64 + n] : wn0[(k - 64) * 64 + n];
        WP0[pkoff(n, k, 128)] = f2h(v);
        v = (k < 64) ? ws1[k * 64 + n] : wn1[(k - 64) * 64 + n];
        WP1[pkoff(n, k, 128)] = f2h(v);
    }
    if (t < 16384) {
        int k = t >> 7, n = t & 127;
        float v = (k < 64) ? ws2[k * 128 + n] : wn2[(k - 64) * 128 + n];
        WP2[pkoff(n, k, 128)] = f2h(v);
    }
    if (t < 131072) {
        int k = t >> 8, n = t & 255;
        float v = (k < 256) ? ws3[k * 256 + n] : wn3[(k - 256) * 256 + n];
        WP3[pkoff(n, k, 512)] = f2h(v);
    }
}

// ---------------------------------------------------------------- node projection -> f16 (dual layout)
__global__ __launch_bounds__(256)
void proj_k(const float* __restrict__ pos, const float* __restrict__ w,
            const float* __restrict__ b, unsigned short* __restrict__ XB0row,
            unsigned short* __restrict__ XB0pk, int n_nodes) {
    int t = blockIdx.x * 256 + threadIdx.x;
    int n = t >> 6, f = t & 63;
    if (n >= n_nodes) return;
    float p0 = pos[n * 3 + 0], p1 = pos[n * 3 + 1], p2 = pos[n * 3 + 2];
    float v = b[f] + p0 * w[f] + p1 * w[64 + f] + p2 * w[128 + f];
    unsigned short h = f2h(v);
    XB0row[(size_t)n * 128 + f] = h;
    XB0pk[pkoff(n, f, 128)] = h;
}

// ---------------------------------------------------------------- CSR mean-aggregate (row-major gather, packed write)
template <int F, int KT>
__global__ __launch_bounds__(256)
void agg_pk(const unsigned short* __restrict__ src, int sstr,
            unsigned short* __restrict__ dpk, int dc,
            const int* __restrict__ rowstart, const unsigned short* __restrict__ esrc,
            const float* __restrict__ degf, int n_nodes) {
    int wave = threadIdx.x >> 6;
    int lane = threadIdx.x & 63;
    int n = blockIdx.x * 4 + wave;
    if (n >= n_nodes) return;
    const int ST = (F == 64) ? 2 : 1;
    int half = (F == 64) ? (lane >> 5) : 0;
    int li   = (F == 64) ? (lane & 31) : lane;
    int e0 = rowstart[n], e1 = rowstart[n + 1];
    float a0 = 0.f, a1 = 0.f;
    int e = e0 + half;
    for (; e + 7 * ST < e1; e += 8 * ST) {
        int s[8];
        unsigned p[8];
        #pragma unroll
        for (int j = 0; j < 8; j++) s[j] = esrc[e + j * ST];
        #pragma unroll
        for (int j = 0; j < 8; j++) p[j] = *(const unsigned*)&src[(size_t)s[j] * sstr + 2 * li];
        #pragma unroll
        for (int j = 0; j < 8; j++) {
            a0 += h2f((unsigned short)(p[j] & 0xffffu));
            a1 += h2f((unsigned short)(p[j] >> 16));
        }
    }
    for (; e + 3 * ST < e1; e += 4 * ST) {
        int s[4];
        unsigned p[4];
        #pragma unroll
        for (int j = 0; j < 4; j++) s[j] = esrc[e + j * ST];
        #pragma unroll
        for (int j = 0; j < 4; j++) p[j] = *(const unsigned*)&src[(size_t)s[j] * sstr + 2 * li];
        #pragma unroll
        for (int j = 0; j < 4; j++) {
            a0 += h2f((unsigned short)(p[j] & 0xffffu));
            a1 += h2f((unsigned short)(p[j] >> 16));
        }
    }
    for (; e < e1; e += ST) {
        int s = esrc[e];
        unsigned p = *(const unsigned*)&src[(size_t)s * sstr + 2 * li];
        a0 += h2f((unsigned short)(p & 0xffffu));
        a1 += h2f((unsigned short)(p >> 16));
    }
    if (F == 64) { a0 += __shfl_xor(a0, 32); a1 += __shfl_xor(a1, 32); }
    float inv = 1.0f / degf[n];
    unsigned out = (unsigned)f2h(a0 * inv) | ((unsigned)f2h(a1 * inv) << 16);
    if (F != 64 || lane < 32) {
        int c = dc + 2 * li;
        *(unsigned*)&dpk[pkoff(n, c, KT)] = out;
    }
}

__device__ inline void atomicMaxFloat(float* addr, float v) {
    if (v >= 0.f) atomicMax((int*)addr, __float_as_int(v));
    else          atomicMin((unsigned int*)addr, __float_as_uint(v));
}

// ---------------------------------------------------------------- direct-register fragment MFMA GEMM
// 256-thread block = 4 INDEPENDENT waves (no barriers), m-split. TLP-first config:
// small per-wave tiles, many waves. Inner loop = 2-deep buffer (compiler reschedules,
// TLP carries the latency hiding). Per-wave LDS repack region; POOL epilogue register-only.
template <int K, int KTA, int MT, int NTB, int POOL>
__global__ __launch_bounds__(256)
void gemm_fr(const unsigned short* __restrict__ Apk, int KA1, int ac1, int ac2,
             const unsigned short* __restrict__ Wpk, const float* __restrict__ bias,
             unsigned short* __restrict__ Drow, int dcol,
             unsigned short* __restrict__ Dpk, int KTD,
             float* __restrict__ pmax, float* __restrict__ psum,
             const int* __restrict__ batch, int M) {
    const int NS = K / 32;
    const int TROW = NTB * 16 + 8;
    const int TSZ = POOL ? 4 : (MT * 16) * TROW;
    __shared__ unsigned short tile_s[4][TSZ];
    int w = threadIdx.x >> 6;
    int lane = threadIdx.x & 63;
    int lm = lane & 15, kb = lane >> 4;
    int rb0 = (blockIdx.x * 4 + w) * MT;
    int nb0 = blockIdx.y * NTB;
    int m0 = rb0 * 16;
    if (m0 >= M) return;            // barrier-free: safe
    unsigned short* tile = tile_s[w];

    f32x4 acc[MT][NTB] = {};

    auto loadf = [&](f16x8* A_, f16x8* B_, int s) {
        int kk = s * 32;
        int phys = (kk < KA1) ? (ac1 + kk) : (ac2 + (kk - KA1));
        size_t ak = (size_t)(phys >> 5) * 512 + (size_t)lane * 8;
        #pragma unroll
        for (int mf = 0; mf < MT; mf++)
            A_[mf] = *(const f16x8*)&Apk[(size_t)(rb0 + mf) * (KTA / 32) * 512 + ak];
        #pragma unroll
        for (int nt = 0; nt < NTB; nt++)
            B_[nt] = *(const f16x8*)&Wpk[((size_t)(nb0 + nt) * (K / 32) + s) * 512 + (size_t)lane * 8];
    };
    auto domfma = [&](f16x8* A_, f16x8* B_) {
        #pragma unroll
        for (int nt = 0; nt < NTB; nt++)
            #pragma unroll
            for (int mf = 0; mf < MT; mf++)
                acc[mf][nt] = __builtin_amdgcn_mfma_f32_16x16x32_f16(A_[mf], B_[nt], acc[mf][nt], 0, 0, 0);
    };

    f16x8 aA[MT], bA[NTB], aB[MT], bB[NTB];
    loadf(aA, bA, 0);
    for (int s = 0; s < NS; s += 2) {
        loadf(aB, bB, s + 1);
        domfma(aA, bA);
        if (s + 2 < NS) loadf(aA, bA, s + 2);
        domfma(aB, bB);
    }

    if (!POOL) {
        #pragma unroll
        for (int nt = 0; nt < NTB; nt++) {
            int colL = nt * 16 + lm;
            float bv = bias[nb0 * 16 + colL];
            #pragma unroll
            for (int mf = 0; mf < MT; mf++) {
                #pragma unroll
                for (int r = 0; r < 4; r++) {
                    float v = acc[mf][nt][r] + bv;
                    v = (v > 0.f) ? v : 0.01f * v;
                    unsigned short h = f2h(v);
                    tile[(mf * 16 + kb * 4 + r) * TROW + colL] = h;
                    int gm = m0 + mf * 16 + kb * 4 + r;
                    if (gm < M) Drow[(size_t)gm * 256 + dcol + nb0 * 16 + colL] = h;
                }
            }
        }
        // per-wave LDS RAW: compiler-inserted lgkmcnt orders this (no barrier needed)
        int dkg0 = (dcol + nb0 * 16) >> 5;
        #pragma unroll
        for (int mf = 0; mf < MT; mf++) {
            #pragma unroll
            for (int kg = 0; kg < NTB / 2; kg++) {
                us8 u = *(const us8*)&tile[(mf * 16 + lm) * TROW + kg * 32 + kb * 8];
                *(us8*)&Dpk[((size_t)(rb0 + mf) * (KTD / 32) + dkg0 + kg) * 512 + (size_t)lane * 8] = u;
            }
        }
    } else {
        int grow[MT * 4];
        #pragma unroll
        for (int mf = 0; mf < MT; mf++)
            #pragma unroll
            for (int r = 0; r < 4; r++) {
                int gm = m0 + mf * 16 + kb * 4 + r;
                grow[mf * 4 + r] = batch[gm < M ? gm : (M - 1)];
            }
        int mlast = m0 + MT * 16 - 1;
        bool uni = (batch[m0] == batch[mlast < M ? mlast : (M - 1)]);
        if (uni) {
            int g = grow[0];
            #pragma unroll
            for (int nt = 0; nt < NTB; nt++) {
                int col = (nb0 + nt) * 16 + lm;
                float bv = bias[col];
                float mx = -INFINITY, sm = 0.f;
                #pragma unroll
                for (int mf = 0; mf < MT; mf++) {
                    #pragma unroll
                    for (int r = 0; r < 4; r++) {
                        int gm = m0 + mf * 16 + kb * 4 + r;
                        if (gm >= M) continue;
                        float v = acc[mf][nt][r] + bv;
                        v = (v > 0.f) ? v : 0.01f * v;
                        mx = fmaxf(mx, v); sm += v;
                    }
                }
                mx = fmaxf(mx, __shfl_xor(mx, 16));
                mx = fmaxf(mx, __shfl_xor(mx, 32));
                sm += __shfl_xor(sm, 16);
                sm += __shfl_xor(sm, 32);
                if (kb == 0 && mx > -INFINITY) {
                    atomicMaxFloat(&pmax[g * 256 + col], mx);
                    atomicAdd(&psum[g * 256 + col], sm);
                }
            }
        } else {
            #pragma unroll
            for (int nt = 0; nt < NTB; nt++) {
                int col = (nb0 + nt) * 16 + lm;
                float bv = bias[col];
                int curg = -1; float mx = -INFINITY, sm = 0.f;
                #pragma unroll
                for (int mf = 0; mf < MT; mf++) {
                    #pragma unroll
                    for (int r = 0; r < 4; r++) {
                        int gm = m0 + mf * 16 + kb * 4 + r;
                        if (gm >= M) continue;
                        int g = grow[mf * 4 + r];
                        if (g != curg) {
                            if (curg >= 0) {
                                atomicMaxFloat(&pmax[curg * 256 + col], mx);
                                atomicAdd(&psum[curg * 256 + col], sm);
                            }
                            curg = g; mx = -INFINITY; sm = 0.f;
                        }
                        float v = acc[mf][nt][r] + bv;
                        v = (v > 0.f) ? v : 0.01f * v;
                        mx = fmaxf(mx, v); sm += v;
                    }
                }
                if (curg >= 0) {
                    atomicMaxFloat(&pmax[curg * 256 + col], mx);
                    atomicAdd(&psum[curg * 256 + col], sm);
                }
            }
        }
    }
}

// ---------------------------------------------------------------- fp32 fused GEMM (dense head)
template <int K, int FOUT>
__global__ __launch_bounds__(256)
void gemm_lrelu(const float* __restrict__ A1, int a1s, int a1c, int KA1,
                const float* __restrict__ A2, int a2s, int a2c,
                const float* __restrict__ W1, const float* __restrict__ W2,
                const float* __restrict__ bias,
                float* __restrict__ D, int dstr, int dcol, int M, int doRelu) {
    const int BM = 64, BN = 64, BK = 16;
    __shared__ float As[BK][BM];
    __shared__ float Bs[BK][BN];
    int tid = threadIdx.x;
    int m0 = blockIdx.x * BM;
    int n0 = blockIdx.y * BN;
    int tx = tid & 15;
    int ty = tid >> 4;
    float acc[4][4] = {};
    int mA = tid >> 2;
    int kA = (tid & 3) * 4;
    int kB = tid >> 4;
    int nB = (tid & 15) * 4;
    for (int k0 = 0; k0 < K; k0 += BK) {
        int kk = k0 + kA;
        const float* Ap; int Asr; int Acc;
        if (kk < KA1) { Ap = A1; Asr = a1s; Acc = a1c + kk; }
        else          { Ap = A2; Asr = a2s; Acc = a2c + (kk - KA1); }
        int gm = m0 + mA;
        float4 av;
        if (gm < M) av = *(const float4*)&Ap[(size_t)gm * Asr + Acc];
        else        av = float4{0.f, 0.f, 0.f, 0.f};
        As[kA + 0][mA] = av.x; As[kA + 1][mA] = av.y;
        As[kA + 2][mA] = av.z; As[kA + 3][mA] = av.w;
        int kw = k0 + kB;
        const float* Wp; int kwl;
        if (kw < K / 2) { Wp = W1; kwl = kw; } else { Wp = W2; kwl = kw - K / 2; }
        float4 bv = *(const float4*)&Wp[(size_t)kwl * FOUT + n0 + nB];
        *(float4*)&Bs[kB][nB] = bv;
        __syncthreads();
        #pragma unroll
        for (int k = 0; k < BK; k++) {
            float a[4], b[4];
            *(float4*)a = *(const float4*)&As[k][ty * 4];
            *(float4*)b = *(const float4*)&Bs[k][tx * 4];
            #pragma unroll
            for (int i = 0; i < 4; i++)
                #pragma unroll
                for (int j = 0; j < 4; j++)
                    acc[i][j] += a[i] * b[j];
        }
        __syncthreads();
    }
    #pragma unroll
    for (int i = 0; i < 4; i++) {
        int gm = m0 + ty * 4 + i;
        if (gm >= M) continue;
        #pragma unroll
        for (int j = 0; j < 4; j++) {
            int gn = n0 + tx * 4 + j;
            float v = acc[i][j] + bias[gn];
            if (doRelu) v = (v > 0.f) ? v : 0.01f * v;
            D[(size_t)gm * dstr + dcol + gn] = v;
        }
    }
}

// ---------------------------------------------------------------- pooling finalize
__global__ __launch_bounds__(256)
void pool_final(const float* __restrict__ pmax, const float* __restrict__ psum,
                const int* __restrict__ batch, float* __restrict__ pooled,
                int G, int n_nodes) {
    int t = blockIdx.x * 256 + threadIdx.x;
    if (t >= G * 256) return;
    int g = t >> 8, f = t & 255;
    int lo = 0, hi = n_nodes;
    while (lo < hi) { int mid = (lo + hi) >> 1; if (batch[mid] < g) lo = mid + 1; else hi = mid; }
    int start = lo;
    lo = start; hi = n_nodes;
    while (lo < hi) { int mid = (lo + hi) >> 1; if (batch[mid] < g + 1) lo = mid + 1; else hi = mid; }
    int end = lo;
    int c = end - start;
    float mx = pmax[t];
    if (c == 0) mx = 0.f;
    pooled[g * 512 + f] = mx;
    pooled[g * 512 + 256 + f] = psum[t] / (float)(c > 0 ? c : 1);
}

// ---------------------------------------------------------------- launcher
extern "C" void kernel_launch(void* const* d_in, const int* in_sizes, int n_in,
                              void* d_out, int out_size, void* d_ws, size_t ws_size,
                              hipStream_t stream) {
    const float* pos   = (const float*)d_in[0];
    const int*   eidx  = (const int*)d_in[1];
    const int*   batch = (const int*)d_in[2];
    const float* w_proj = (const float*)d_in[3];
    const float* b_proj = (const float*)d_in[4];
    const float* ws0 = (const float*)d_in[5];  const float* wn0 = (const float*)d_in[6];  const float* bb0 = (const float*)d_in[7];
    const float* ws1 = (const float*)d_in[8];  const float* wn1 = (const float*)d_in[9];  const float* bb1 = (const float*)d_in[10];
    const float* ws2 = (const float*)d_in[11]; const float* wn2 = (const float*)d_in[12]; const float* bb2 = (const float*)d_in[13];
    const float* ws3 = (const float*)d_in[14]; const float* wn3 = (const float*)d_in[15]; const float* bb3 = (const float*)d_in[16];
    const float* wd1 = (const float*)d_in[17]; const float* bd1 = (const float*)d_in[18];
    const float* wd2 = (const float*)d_in[19]; const float* bd2 = (const float*)d_in[20];

    int N = in_sizes[0] / 3;
    int E = in_sizes[1] / 2;
    int G = out_size / 256;
    const int* esrc_in = eidx;
    const int* edst_in = eidx + E;

    int gbx1 = (N + 63) / 64;       // MT=1 blocks: 4 waves x 16 rows
    int gbx2 = (N + 127) / 128;     // MT=2 blocks: 4 waves x 32 rows
    int NRB = gbx1 * 4 + 8;         // row-frags covered (3128) + pad
    int NB  = (N + 127) >> 7;       // CSR node buckets

    char* base = (char*)d_ws;
    size_t off = 0;
    auto alloc = [&](size_t bytes) -> void* {
        void* p = base + off;
        off = (off + bytes + 255) & ~(size_t)255;
        return p;
    };
    int*   rowstart = (int*)alloc((size_t)(N + 1) * 4);
    float* degf     = (float*)alloc((size_t)N * 4);
    int*   bcnt     = (int*)alloc((size_t)512 * 4);
    int*   bbase    = (int*)alloc((size_t)513 * 4);
    int*   bcur     = (int*)alloc((size_t)512 * 4);
    unsigned* bedge = (unsigned*)alloc((size_t)E * 4);
    unsigned short* esrc = (unsigned short*)alloc((size_t)E * 2);
    unsigned short* XB0row = (unsigned short*)alloc((size_t)N * 128 * 2);
    unsigned short* XB0pk  = (unsigned short*)alloc((size_t)NRB * 16 * 128 * 2);
    unsigned short* XBrow  = (unsigned short*)alloc((size_t)N * 256 * 2);
    unsigned short* XBpk   = (unsigned short*)alloc((size_t)NRB * 16 * 512 * 2);
    float* pooled   = (float*)alloc((size_t)G * 512 * 4);
    float* hid      = (float*)alloc((size_t)G * 512 * 4);
    float* pmax     = (float*)alloc((size_t)G * 256 * 4);
    float* psum     = (float*)alloc((size_t)G * 256 * 4);
    unsigned short* WP0 = (unsigned short*)alloc((size_t)64 * 128 * 2);
    unsigned short* WP1 = (unsigned short*)alloc((size_t)64 * 128 * 2);
    unsigned short* WP2 = (unsigned short*)alloc((size_t)128 * 128 * 2);
    unsigned short* WP3 = (unsigned short*)alloc((size_t)256 * 512 * 2);

    // ---- merged prep: bcnt zero + pool init + weight packing ----
    prep_k<<<512, 256, 0, stream>>>(bcnt, pmax, psum, G,
                                    ws0, wn0, WP0, ws1, wn1, WP1,
                                    ws2, wn2, WP2, ws3, wn3, WP3);

    // ---- bucketed CSR build ----
    int eb = (E + ECH - 1) / ECH;
    bucket_hist<<<eb, 256, 0, stream>>>(edst_in, bcnt, E, NB);
    bucket_scan<<<1, 512, 0, stream>>>(bcnt, bbase, bcur, rowstart, NB, N);
    bucket_scatter<<<eb, 256, 0, stream>>>(esrc_in, edst_in, bcur, bedge, E, NB);
    node_csr<<<NB, 256, 0, stream>>>(bedge, bbase, rowstart, degf, esrc, N);

    // ---- projection ----
    proj_k<<<(N * 64 + 255) / 256, 256, 0, stream>>>(pos, w_proj, b_proj, XB0row, XB0pk, N);

    int ab = (N + 3) / 4;

    // layer 0: agg(x) -> XB0pk cols 64..128; gemm (MT=1, 3128 waves) -> h0
    agg_pk<64, 128><<<ab, 256, 0, stream>>>(XB0row, 128, XB0pk, 64, rowstart, esrc, degf, N);
    gemm_fr<128, 128, 1, 4, 0><<<dim3(gbx1, 1), 256, 0, stream>>>(
        XB0pk, 128, 0, 0, WP0, bb0, XBrow, 0, XBpk, 512, nullptr, nullptr, nullptr, N);

    // layer 1: agg(h0) -> XBpk cols 256..320; gemm (MT=1) -> h1
    agg_pk<64, 512><<<ab, 256, 0, stream>>>(XBrow, 256, XBpk, 256, rowstart, esrc, degf, N);
    gemm_fr<128, 512, 1, 4, 0><<<dim3(gbx1, 1), 256, 0, stream>>>(
        XBpk, 64, 0, 256, WP1, bb1, XBrow, 64, XBpk, 512, nullptr, nullptr, nullptr, N);

    // layer 2: agg(h1) -> XBpk cols 320..384; gemm (MT=1, 6256 waves) -> h2
    agg_pk<64, 512><<<ab, 256, 0, stream>>>(XBrow + 64, 256, XBpk, 320, rowstart, esrc, degf, N);
    gemm_fr<128, 512, 1, 4, 0><<<dim3(gbx1, 2), 256, 0, stream>>>(
        XBpk, 64, 64, 320, WP2, bb2, XBrow, 128, XBpk, 512, nullptr, nullptr, nullptr, N);

    // layer 3: agg(h2) -> XBpk cols 384..512; K=512 gemm (MT=2, grid.y=4, 6256 waves) + fused pooling
    agg_pk<128, 512><<<ab, 256, 0, stream>>>(XBrow + 128, 256, XBpk, 384, rowstart, esrc, degf, N);
    gemm_fr<512, 512, 2, 4, 1><<<dim3(gbx2, 4), 256, 0, stream>>>(
        XBpk, 512, 0, 0, WP3, bb3, nullptr, 0, nullptr, 512, pmax, psum, batch, N);
    pool_final<<<(G * 256 + 255) / 256, 256, 0, stream>>>(pmax, psum, batch, pooled, G, N);

    // ---- dense head (fp32) ----
    gemm_lrelu<512, 512><<<dim3((G + 63) / 64, 8), 256, 0, stream>>>(
        pooled, 512, 0, 512, pooled, 512, 0, wd1, wd1 + 256 * 512, bd1, hid, 512, 0, G, 1);
    gemm_lrelu<512, 256><<<dim3((G + 63) / 64, 4), 256, 0, stream>>>(
        hid, 512, 0, 512, hid, 512, 0, wd2, wd2 + 256 * 256, bd2, (float*)d_out, 256, 0, G, 0);
}

// Round 15
// 281.563 us; speedup vs baseline: 1.0786x; 1.0786x over previous
//
#include <hip/hip_runtime.h>
#include <math.h>

typedef _Float16 f16x8 __attribute__((ext_vector_type(8)));
typedef unsigned short us8 __attribute__((ext_vector_type(8)));
typedef float f32x4 __attribute__((ext_vector_type(4)));

__device__ inline unsigned short f2h(float f) {
    _Float16 h = (_Float16)f;
    return *(unsigned short*)&h;
}
__device__ inline float h2f(unsigned short u) {
    _Float16 h = *(_Float16*)&u;
    return (float)h;
}

// fragment-packed offset (in halves) for element (row, col) in a buffer with KT cols
__device__ __forceinline__ size_t pkoff(int row, int col, int KT) {
    return ((size_t)(row >> 4) * (KT >> 5) + (col >> 5)) * 512
         + (size_t)(((col >> 3) & 3) * 128 + ((row & 15) << 3) + (col & 7));
}

// ============================================================ bucketed CSR build
#define ECH 4096

__global__ __launch_bounds__(256)
void bucket_hist(const int* __restrict__ edst, int* __restrict__ bcnt, int E, int NB) {
    __shared__ int h[512];
    int tid = threadIdx.x;
    for (int i = tid; i < NB; i += 256) h[i] = 0;
    __syncthreads();
    int c0 = blockIdx.x * ECH, c1 = min(c0 + ECH, E);
    for (int e = c0 + tid; e < c1; e += 256) atomicAdd(&h[edst[e] >> 7], 1);
    __syncthreads();
    for (int i = tid; i < NB; i += 256) if (h[i]) atomicAdd(&bcnt[i], h[i]);
}

__global__ __launch_bounds__(512)
void bucket_scan(const int* __restrict__ bcnt, int* __restrict__ bbase,
                 int* __restrict__ bcur, int* __restrict__ rowstart, int NB, int n) {
    __shared__ int ws[8];
    int tid = threadIdx.x, lane = tid & 63, wid = tid >> 6;
    int v = (tid < NB) ? bcnt[tid] : 0;
    int x = v;
    for (int d = 1; d < 64; d <<= 1) { int y = __shfl_up(x, d); if (lane >= d) x += y; }
    if (lane == 63) ws[wid] = x;
    __syncthreads();
    int off = 0;
    for (int w = 0; w < wid; w++) off += ws[w];
    int excl = x - v + off;
    if (tid < NB) { bbase[tid] = excl; bcur[tid] = excl; }
    if (tid == 0) {
        int tot = 0;
        for (int w = 0; w < 8; w++) tot += ws[w];
        bbase[NB] = tot;
        rowstart[n] = tot;
    }
}

__global__ __launch_bounds__(256)
void bucket_scatter(const int* __restrict__ esrc_in, const int* __restrict__ edst_in,
                    int* __restrict__ bcur, unsigned* __restrict__ bedge, int E, int NB) {
    __shared__ int h[512];
    __shared__ int rb[512];
    int tid = threadIdx.x;
    for (int i = tid; i < NB; i += 256) h[i] = 0;
    __syncthreads();
    int c0 = blockIdx.x * ECH, c1 = min(c0 + ECH, E);
    for (int e = c0 + tid; e < c1; e += 256) atomicAdd(&h[edst_in[e] >> 7], 1);
    __syncthreads();
    for (int i = tid; i < NB; i += 256) {
        rb[i] = h[i] ? atomicAdd(&bcur[i], h[i]) : 0;
        h[i] = 0;   // reuse as local cursor
    }
    __syncthreads();
    for (int e = c0 + tid; e < c1; e += 256) {
        int dst = edst_in[e], src = esrc_in[e];
        int b = dst >> 7;
        int o = atomicAdd(&h[b], 1);
        bedge[rb[b] + o] = (unsigned)src | ((unsigned)(dst & 127) << 16);
    }
}

__global__ __launch_bounds__(256)
void node_csr(const unsigned* __restrict__ bedge, const int* __restrict__ bbase,
              int* __restrict__ rowstart, float* __restrict__ degf,
              unsigned short* __restrict__ esrc, int n) {
    __shared__ int cnt[128];
    __shared__ int cur[128];
    __shared__ int ws4[4];
    int b = blockIdx.x, tid = threadIdx.x;
    int lane = tid & 63, wid = tid >> 6;
    int n0 = b << 7;
    int eb0 = bbase[b], eb1 = bbase[b + 1];
    if (tid < 128) cnt[tid] = 0;
    __syncthreads();
    for (int e = eb0 + tid; e < eb1; e += 256) atomicAdd(&cnt[(bedge[e] >> 16) & 127], 1);
    __syncthreads();
    int v = (tid < 128) ? cnt[tid] : 0;
    int x = v;
    for (int d = 1; d < 64; d <<= 1) { int y = __shfl_up(x, d); if (lane >= d) x += y; }
    if (lane == 63) ws4[wid] = x;
    __syncthreads();
    int off = 0;
    for (int w = 0; w < wid; w++) off += ws4[w];
    int excl = x - v + off;
    if (tid < 128 && n0 + tid < n) {
        rowstart[n0 + tid] = eb0 + excl;
        cur[tid] = eb0 + excl;
        degf[n0 + tid] = (float)(v > 0 ? v : 1);
    }
    __syncthreads();
    for (int e = eb0 + tid; e < eb1; e += 256) {
        unsigned u = bedge[e];
        int p = atomicAdd(&cur[(u >> 16) & 127], 1);
        esrc[p] = (unsigned short)(u & 0xffffu);
    }
}

// ---------------------------------------------------------------- merged prep:
// zero bcnt, init pool, pack WP1-3, combine layer-0 weights (Wp@Ws0 / Wp@Wn0), pack pos16
__global__ __launch_bounds__(256)
void prep_k(int* __restrict__ bcnt, float* __restrict__ pmax, float* __restrict__ psum, int G,
            const float* __restrict__ ws1, const float* __restrict__ wn1, unsigned short* __restrict__ WP1,
            const float* __restrict__ ws2, const float* __restrict__ wn2, unsigned short* __restrict__ WP2,
            const float* __restrict__ ws3, const float* __restrict__ wn3, unsigned short* __restrict__ WP3,
            const float* __restrict__ wp, const float* __restrict__ bp,
            const float* __restrict__ ws0, const float* __restrict__ wn0, const float* __restrict__ bb0,
            float* __restrict__ W0c, float* __restrict__ b0c,
            const float* __restrict__ pos, unsigned short* __restrict__ pos16, int N) {
    int t = blockIdx.x * 256 + threadIdx.x;
    if (t < 512) bcnt[t] = 0;
    if (t < G * 256) { pmax[t] = -INFINITY; psum[t] = 0.f; }
    if (t < 8192) {
        int k = t >> 6, n = t & 63;
        float v = (k < 64) ? ws1[k * 64 + n] : wn1[(k - 64) * 64 + n];
        WP1[pkoff(n, k, 128)] = f2h(v);
    }
    if (t < 16384) {
        int k = t >> 7, n = t & 127;
        float v = (k < 64) ? ws2[k * 128 + n] : wn2[(k - 64) * 128 + n];
        WP2[pkoff(n, k, 128)] = f2h(v);
    }
    if (t < 131072) {
        int k = t >> 8, n = t & 255;
        float v = (k < 256) ? ws3[k * 256 + n] : wn3[(k - 256) * 256 + n];
        WP3[pkoff(n, k, 512)] = f2h(v);
    }
    if (t < 384) {  // W0c[j][f]: j<3 from Ws0, j>=3 from Wn0
        int j = t / 64, f = t & 63;
        const float* W = (j < 3) ? ws0 : wn0;
        int jj = (j < 3) ? j : j - 3;
        float acc = 0.f;
        for (int c = 0; c < 64; c++) acc += wp[jj * 64 + c] * W[c * 64 + f];
        W0c[j * 64 + f] = acc;
    }
    if (t < 64) {   // b0c[f] = bp@(Ws0+Wn0) + bb0
        float acc = bb0[t];
        for (int c = 0; c < 64; c++) acc += bp[c] * (ws0[c * 64 + t] + wn0[c * 64 + t]);
        b0c[t] = acc;
    }
    if (t < 4 * N) {  // pos16: [N][4] f16 (8B-aligned rows; comp 3 = 0)
        int n = t >> 2, j = t & 3;
        pos16[t] = (j < 3) ? f2h(pos[n * 3 + j]) : 0;
    }
}

// ---------------------------------------------------------------- fused layer 0:
// h0 = lrelu([pos | mean_nbr(pos)] @ W0c + b0c)   (K=6, linearity of proj+mean)
// One wave per node: lanes gather 8B pos16 rows (1 line/edge), shfl-reduce, 6 MACs per f.
__global__ __launch_bounds__(256)
void l0_k(const float* __restrict__ pos, const unsigned short* __restrict__ pos16,
          const float* __restrict__ W0c, const float* __restrict__ b0c,
          const int* __restrict__ rowstart, const unsigned short* __restrict__ esrc,
          const float* __restrict__ degf,
          unsigned short* __restrict__ XBrow, unsigned short* __restrict__ XBpk, int n_nodes) {
    int wave = threadIdx.x >> 6, lane = threadIdx.x & 63;
    int n = blockIdx.x * 4 + wave;
    if (n >= n_nodes) return;
    int e0 = rowstart[n], e1 = rowstart[n + 1];
    float ax = 0.f, ay = 0.f, az = 0.f;
    for (int e = e0 + lane; e < e1; e += 64) {
        int s = esrc[e];
        uint2 q = *(const uint2*)&pos16[(size_t)s * 4];
        ax += h2f((unsigned short)(q.x & 0xffffu));
        ay += h2f((unsigned short)(q.x >> 16));
        az += h2f((unsigned short)(q.y & 0xffffu));
    }
    #pragma unroll
    for (int d = 32; d; d >>= 1) {
        ax += __shfl_xor(ax, d);
        ay += __shfl_xor(ay, d);
        az += __shfl_xor(az, d);
    }
    float inv = 1.0f / degf[n];
    ax *= inv; ay *= inv; az *= inv;
    float px = pos[n * 3 + 0], py = pos[n * 3 + 1], pz = pos[n * 3 + 2];
    int f = lane;
    float v = b0c[f] + px * W0c[f] + py * W0c[64 + f] + pz * W0c[128 + f]
            + ax * W0c[192 + f] + ay * W0c[256 + f] + az * W0c[320 + f];
    v = (v > 0.f) ? v : 0.01f * v;
    unsigned short h = f2h(v);
    XBrow[(size_t)n * 256 + f] = h;
    XBpk[pkoff(n, f, 512)] = h;
}

// ---------------------------------------------------------------- CSR mean-aggregate (row-major gather, packed write)
template <int F, int KT>
__global__ __launch_bounds__(256)
void agg_pk(const unsigned short* __restrict__ src, int sstr,
            unsigned short* __restrict__ dpk, int dc,
            const int* __restrict__ rowstart, const unsigned short* __restrict__ esrc,
            const float* __restrict__ degf, int n_nodes) {
    int wave = threadIdx.x >> 6;
    int lane = threadIdx.x & 63;
    int n = blockIdx.x * 4 + wave;
    if (n >= n_nodes) return;
    const int ST = (F == 64) ? 2 : 1;
    int half = (F == 64) ? (lane >> 5) : 0;
    int li   = (F == 64) ? (lane & 31) : lane;
    int e0 = rowstart[n], e1 = rowstart[n + 1];
    float a0 = 0.f, a1 = 0.f;
    int e = e0 + half;
    for (; e + 7 * ST < e1; e += 8 * ST) {
        int s[8];
        unsigned p[8];
        #pragma unroll
        for (int j = 0; j < 8; j++) s[j] = esrc[e + j * ST];
        #pragma unroll
        for (int j = 0; j < 8; j++) p[j] = *(const unsigned*)&src[(size_t)s[j] * sstr + 2 * li];
        #pragma unroll
        for (int j = 0; j < 8; j++) {
            a0 += h2f((unsigned short)(p[j] & 0xffffu));
            a1 += h2f((unsigned short)(p[j] >> 16));
        }
    }
    for (; e + 3 * ST < e1; e += 4 * ST) {
        int s[4];
        unsigned p[4];
        #pragma unroll
        for (int j = 0; j < 4; j++) s[j] = esrc[e + j * ST];
        #pragma unroll
        for (int j = 0; j < 4; j++) p[j] = *(const unsigned*)&src[(size_t)s[j] * sstr + 2 * li];
        #pragma unroll
        for (int j = 0; j < 4; j++) {
            a0 += h2f((unsigned short)(p[j] & 0xffffu));
            a1 += h2f((unsigned short)(p[j] >> 16));
        }
    }
    for (; e < e1; e += ST) {
        int s = esrc[e];
        unsigned p = *(const unsigned*)&src[(size_t)s * sstr + 2 * li];
        a0 += h2f((unsigned short)(p & 0xffffu));
        a1 += h2f((unsigned short)(p >> 16));
    }
    if (F == 64) { a0 += __shfl_xor(a0, 32); a1 += __shfl_xor(a1, 32); }
    float inv = 1.0f / degf[n];
    unsigned out = (unsigned)f2h(a0 * inv) | ((unsigned)f2h(a1 * inv) << 16);
    if (F != 64 || lane < 32) {
        int c = dc + 2 * li;
        *(unsigned*)&dpk[pkoff(n, c, KT)] = out;
    }
}

__device__ inline void atomicMaxFloat(float* addr, float v) {
    if (v >= 0.f) atomicMax((int*)addr, __float_as_int(v));
    else          atomicMin((unsigned int*)addr, __float_as_uint(v));
}

// ---------------------------------------------------------------- direct-register fragment MFMA GEMM
// 256-thread block = 4 INDEPENDENT waves (no barriers), m-split.
template <int K, int KTA, int MT, int NTB, int POOL>
__global__ __launch_bounds__(256)
void gemm_fr(const unsigned short* __restrict__ Apk, int KA1, int ac1, int ac2,
             const unsigned short* __restrict__ Wpk, const float* __restrict__ bias,
             unsigned short* __restrict__ Drow, int dcol,
             unsigned short* __restrict__ Dpk, int KTD,
             float* __restrict__ pmax, float* __restrict__ psum,
             const int* __restrict__ batch, int M) {
    const int NS = K / 32;
    const int TROW = NTB * 16 + 8;
    const int TSZ = POOL ? 4 : (MT * 16) * TROW;
    __shared__ unsigned short tile_s[4][TSZ];
    int w = threadIdx.x >> 6;
    int lane = threadIdx.x & 63;
    int lm = lane & 15, kb = lane >> 4;
    int rb0 = (blockIdx.x * 4 + w) * MT;
    int nb0 = blockIdx.y * NTB;
    int m0 = rb0 * 16;
    if (m0 >= M) return;            // barrier-free: safe
    unsigned short* tile = tile_s[w];

    f32x4 acc[MT][NTB] = {};

    auto loadf = [&](f16x8* A_, f16x8* B_, int s) {
        int kk = s * 32;
        int phys = (kk < KA1) ? (ac1 + kk) : (ac2 + (kk - KA1));
        size_t ak = (size_t)(phys >> 5) * 512 + (size_t)lane * 8;
        #pragma unroll
        for (int mf = 0; mf < MT; mf++)
            A_[mf] = *(const f16x8*)&Apk[(size_t)(rb0 + mf) * (KTA / 32) * 512 + ak];
        #pragma unroll
        for (int nt = 0; nt < NTB; nt++)
            B_[nt] = *(const f16x8*)&Wpk[((size_t)(nb0 + nt) * (K / 32) + s) * 512 + (size_t)lane * 8];
    };
    auto domfma = [&](f16x8* A_, f16x8* B_) {
        #pragma unroll
        for (int nt = 0; nt < NTB; nt++)
            #pragma unroll
            for (int mf = 0; mf < MT; mf++)
                acc[mf][nt] = __builtin_amdgcn_mfma_f32_16x16x32_f16(A_[mf], B_[nt], acc[mf][nt], 0, 0, 0);
    };

    f16x8 aA[MT], bA[NTB], aB[MT], bB[NTB];
    loadf(aA, bA, 0);
    for (int s = 0; s < NS; s += 2) {
        loadf(aB, bB, s + 1);
        domfma(aA, bA);
        if (s + 2 < NS) loadf(aA, bA, s + 2);
        domfma(aB, bB);
    }

    if (!POOL) {
        #pragma unroll
        for (int nt = 0; nt < NTB; nt++) {
            int colL = nt * 16 + lm;
            float bv = bias[nb0 * 16 + colL];
            #pragma unroll
            for (int mf = 0; mf < MT; mf++) {
                #pragma unroll
                for (int r = 0; r < 4; r++) {
                    float v = acc[mf][nt][r] + bv;
                    v = (v > 0.f) ? v : 0.01f * v;
                    unsigned short h = f2h(v);
                    tile[(mf * 16 + kb * 4 + r) * TROW + colL] = h;
                    int gm = m0 + mf * 16 + kb * 4 + r;
                    if (gm < M) Drow[(size_t)gm * 256 + dcol + nb0 * 16 + colL] = h;
                }
            }
        }
        // per-wave LDS RAW: compiler-inserted lgkmcnt orders this (no barrier needed)
        int dkg0 = (dcol + nb0 * 16) >> 5;
        #pragma unroll
        for (int mf = 0; mf < MT; mf++) {
            #pragma unroll
            for (int kg = 0; kg < NTB / 2; kg++) {
                us8 u = *(const us8*)&tile[(mf * 16 + lm) * TROW + kg * 32 + kb * 8];
                *(us8*)&Dpk[((size_t)(rb0 + mf) * (KTD / 32) + dkg0 + kg) * 512 + (size_t)lane * 8] = u;
            }
        }
    } else {
        int grow[MT * 4];
        #pragma unroll
        for (int mf = 0; mf < MT; mf++)
            #pragma unroll
            for (int r = 0; r < 4; r++) {
                int gm = m0 + mf * 16 + kb * 4 + r;
                grow[mf * 4 + r] = batch[gm < M ? gm : (M - 1)];
            }
        int mlast = m0 + MT * 16 - 1;
        bool uni = (batch[m0] == batch[mlast < M ? mlast : (M - 1)]);
        if (uni) {
            int g = grow[0];
            #pragma unroll
            for (int nt = 0; nt < NTB; nt++) {
                int col = (nb0 + nt) * 16 + lm;
                float bv = bias[col];
                float mx = -INFINITY, sm = 0.f;
                #pragma unroll
                for (int mf = 0; mf < MT; mf++) {
                    #pragma unroll
                    for (int r = 0; r < 4; r++) {
                        int gm = m0 + mf * 16 + kb * 4 + r;
                        if (gm >= M) continue;
                        float v = acc[mf][nt][r] + bv;
                        v = (v > 0.f) ? v : 0.01f * v;
                        mx = fmaxf(mx, v); sm += v;
                    }
                }
                mx = fmaxf(mx, __shfl_xor(mx, 16));
                mx = fmaxf(mx, __shfl_xor(mx, 32));
                sm += __shfl_xor(sm, 16);
                sm += __shfl_xor(sm, 32);
                if (kb == 0 && mx > -INFINITY) {
                    atomicMaxFloat(&pmax[g * 256 + col], mx);
                    atomicAdd(&psum[g * 256 + col], sm);
                }
            }
        } else {
            #pragma unroll
            for (int nt = 0; nt < NTB; nt++) {
                int col = (nb0 + nt) * 16 + lm;
                float bv = bias[col];
                int curg = -1; float mx = -INFINITY, sm = 0.f;
                #pragma unroll
                for (int mf = 0; mf < MT; mf++) {
                    #pragma unroll
                    for (int r = 0; r < 4; r++) {
                        int gm = m0 + mf * 16 + kb * 4 + r;
                        if (gm >= M) continue;
                        int g = grow[mf * 4 + r];
                        if (g != curg) {
                            if (curg >= 0) {
                                atomicMaxFloat(&pmax[curg * 256 + col], mx);
                                atomicAdd(&psum[curg * 256 + col], sm);
                            }
                            curg = g; mx = -INFINITY; sm = 0.f;
                        }
                        float v = acc[mf][nt][r] + bv;
                        v = (v > 0.f) ? v : 0.01f * v;
                        mx = fmaxf(mx, v); sm += v;
                    }
                }
                if (curg >= 0) {
                    atomicMaxFloat(&pmax[curg * 256 + col], mx);
                    atomicAdd(&psum[curg * 256 + col], sm);
                }
            }
        }
    }
}

// ---------------------------------------------------------------- fp32 fused GEMM (dense head)
template <int K, int FOUT>
__global__ __launch_bounds__(256)
void gemm_lrelu(const float* __restrict__ A1, int a1s, int a1c, int KA1,
                const float* __restrict__ A2, int a2s, int a2c,
                const float* __restrict__ W1, const float* __restrict__ W2,
                const float* __restrict__ bias,
                float* __restrict__ D, int dstr, int dcol, int M, int doRelu) {
    const int BM = 64, BN = 64, BK = 16;
    __shared__ float As[BK][BM];
    __shared__ float Bs[BK][BN];
    int tid = threadIdx.x;
    int m0 = blockIdx.x * BM;
    int n0 = blockIdx.y * BN;
    int tx = tid & 15;
    int ty = tid >> 4;
    float acc[4][4] = {};
    int mA = tid >> 2;
    int kA = (tid & 3) * 4;
    int kB = tid >> 4;
    int nB = (tid & 15) * 4;
    for (int k0 = 0; k0 < K; k0 += BK) {
        int kk = k0 + kA;
        const float* Ap; int Asr; int Acc;
        if (kk < KA1) { Ap = A1; Asr = a1s; Acc = a1c + kk; }
        else          { Ap = A2; Asr = a2s; Acc = a2c + (kk - KA1); }
        int gm = m0 + mA;
        float4 av;
        if (gm < M) av = *(const float4*)&Ap[(size_t)gm * Asr + Acc];
        else        av = float4{0.f, 0.f, 0.f, 0.f};
        As[kA + 0][mA] = av.x; As[kA + 1][mA] = av.y;
        As[kA + 2][mA] = av.z; As[kA + 3][mA] = av.w;
        int kw = k0 + kB;
        const float* Wp; int kwl;
        if (kw < K / 2) { Wp = W1; kwl = kw; } else { Wp = W2; kwl = kw - K / 2; }
        float4 bv = *(const float4*)&Wp[(size_t)kwl * FOUT + n0 + nB];
        *(float4*)&Bs[kB][nB] = bv;
        __syncthreads();
        #pragma unroll
        for (int k = 0; k < BK; k++) {
            float a[4], b[4];
            *(float4*)a = *(const float4*)&As[k][ty * 4];
            *(float4*)b = *(const float4*)&Bs[k][tx * 4];
            #pragma unroll
            for (int i = 0; i < 4; i++)
                #pragma unroll
                for (int j = 0; j < 4; j++)
                    acc[i][j] += a[i] * b[j];
        }
        __syncthreads();
    }
    #pragma unroll
    for (int i = 0; i < 4; i++) {
        int gm = m0 + ty * 4 + i;
        if (gm >= M) continue;
        #pragma unroll
        for (int j = 0; j < 4; j++) {
            int gn = n0 + tx * 4 + j;
            float v = acc[i][j] + bias[gn];
            if (doRelu) v = (v > 0.f) ? v : 0.01f * v;
            D[(size_t)gm * dstr + dcol + gn] = v;
        }
    }
}

// ---------------------------------------------------------------- pooling finalize
__global__ __launch_bounds__(256)
void pool_final(const float* __restrict__ pmax, const float* __restrict__ psum,
                const int* __restrict__ batch, float* __restrict__ pooled,
                int G, int n_nodes) {
    int t = blockIdx.x * 256 + threadIdx.x;
    if (t >= G * 256) return;
    int g = t >> 8, f = t & 255;
    int lo = 0, hi = n_nodes;
    while (lo < hi) { int mid = (lo + hi) >> 1; if (batch[mid] < g) lo = mid + 1; else hi = mid; }
    int start = lo;
    lo = start; hi = n_nodes;
    while (lo < hi) { int mid = (lo + hi) >> 1; if (batch[mid] < g + 1) lo = mid + 1; else hi = mid; }
    int end = lo;
    int c = end - start;
    float mx = pmax[t];
    if (c == 0) mx = 0.f;
    pooled[g * 512 + f] = mx;
    pooled[g * 512 + 256 + f] = psum[t] / (float)(c > 0 ? c : 1);
}

// ---------------------------------------------------------------- launcher
extern "C" void kernel_launch(void* const* d_in, const int* in_sizes, int n_in,
                              void* d_out, int out_size, void* d_ws, size_t ws_size,
                              hipStream_t stream) {
    const float* pos   = (const float*)d_in[0];
    const int*   eidx  = (const int*)d_in[1];
    const int*   batch = (const int*)d_in[2];
    const float* w_proj = (const float*)d_in[3];
    const float* b_proj = (const float*)d_in[4];
    const float* ws0 = (const float*)d_in[5];  const float* wn0 = (const float*)d_in[6];  const float* bb0 = (const float*)d_in[7];
    const float* ws1 = (const float*)d_in[8];  const float* wn1 = (const float*)d_in[9];  const float* bb1 = (const float*)d_in[10];
    const float* ws2 = (const float*)d_in[11]; const float* wn2 = (const float*)d_in[12]; const float* bb2 = (const float*)d_in[13];
    const float* ws3 = (const float*)d_in[14]; const float* wn3 = (const float*)d_in[15]; const float* bb3 = (const float*)d_in[16];
    const float* wd1 = (const float*)d_in[17]; const float* bd1 = (const float*)d_in[18];
    const float* wd2 = (const float*)d_in[19]; const float* bd2 = (const float*)d_in[20];

    int N = in_sizes[0] / 3;
    int E = in_sizes[1] / 2;
    int G = out_size / 256;
    const int* esrc_in = eidx;
    const int* edst_in = eidx + E;

    int gbx1 = (N + 63) / 64;       // MT=1 blocks: 4 waves x 16 rows
    int gbx2 = (N + 127) / 128;     // MT=2 blocks: 4 waves x 32 rows
    int NRB = gbx1 * 4 + 8;         // row-frags covered + pad
    int NB  = (N + 127) >> 7;       // CSR node buckets

    char* base = (char*)d_ws;
    size_t off = 0;
    auto alloc = [&](size_t bytes) -> void* {
        void* p = base + off;
        off = (off + bytes + 255) & ~(size_t)255;
        return p;
    };
    int*   rowstart = (int*)alloc((size_t)(N + 1) * 4);
    float* degf     = (float*)alloc((size_t)N * 4);
    int*   bcnt     = (int*)alloc((size_t)512 * 4);
    int*   bbase    = (int*)alloc((size_t)513 * 4);
    int*   bcur     = (int*)alloc((size_t)512 * 4);
    unsigned* bedge = (unsigned*)alloc((size_t)E * 4);
    unsigned short* esrc = (unsigned short*)alloc((size_t)E * 2);
    unsigned short* pos16 = (unsigned short*)alloc((size_t)N * 4 * 2);
    float* W0c      = (float*)alloc((size_t)6 * 64 * 4);
    float* b0c      = (float*)alloc((size_t)64 * 4);
    unsigned short* XBrow  = (unsigned short*)alloc((size_t)N * 256 * 2);
    unsigned short* XBpk   = (unsigned short*)alloc((size_t)NRB * 16 * 512 * 2);
    float* pooled   = (float*)alloc((size_t)G * 512 * 4);
    float* hid      = (float*)alloc((size_t)G * 512 * 4);
    float* pmax     = (float*)alloc((size_t)G * 256 * 4);
    float* psum     = (float*)alloc((size_t)G * 256 * 4);
    unsigned short* WP1 = (unsigned short*)alloc((size_t)64 * 128 * 2);
    unsigned short* WP2 = (unsigned short*)alloc((size_t)128 * 128 * 2);
    unsigned short* WP3 = (unsigned short*)alloc((size_t)256 * 512 * 2);

    // ---- merged prep ----
    int prep_threads = 4 * N > 131072 ? 4 * N : 131072;
    prep_k<<<(prep_threads + 255) / 256, 256, 0, stream>>>(
        bcnt, pmax, psum, G,
        ws1, wn1, WP1, ws2, wn2, WP2, ws3, wn3, WP3,
        w_proj, b_proj, ws0, wn0, bb0, W0c, b0c, pos, pos16, N);

    // ---- bucketed CSR build ----
    int eb = (E + ECH - 1) / ECH;
    bucket_hist<<<eb, 256, 0, stream>>>(edst_in, bcnt, E, NB);
    bucket_scan<<<1, 512, 0, stream>>>(bcnt, bbase, bcur, rowstart, NB, N);
    bucket_scatter<<<eb, 256, 0, stream>>>(esrc_in, edst_in, bcur, bedge, E, NB);
    node_csr<<<NB, 256, 0, stream>>>(bedge, bbase, rowstart, degf, esrc, N);

    int ab = (N + 3) / 4;

    // layer 0 (fused proj+agg+gemm via linearity): -> h0 (XBrow cols 0-63 + XBpk cols 0-63)
    l0_k<<<ab, 256, 0, stream>>>(pos, pos16, W0c, b0c, rowstart, esrc, degf, XBrow, XBpk, N);

    // layer 1: agg(h0) -> XBpk cols 256..320; gemm (MT=1) -> h1
    agg_pk<64, 512><<<ab, 256, 0, stream>>>(XBrow, 256, XBpk, 256, rowstart, esrc, degf, N);
    gemm_fr<128, 512, 1, 4, 0><<<dim3(gbx1, 1), 256, 0, stream>>>(
        XBpk, 64, 0, 256, WP1, bb1, XBrow, 64, XBpk, 512, nullptr, nullptr, nullptr, N);

    // layer 2: agg(h1) -> XBpk cols 320..384; gemm (MT=1, grid.y=2) -> h2
    agg_pk<64, 512><<<ab, 256, 0, stream>>>(XBrow + 64, 256, XBpk, 320, rowstart, esrc, degf, N);
    gemm_fr<128, 512, 1, 4, 0><<<dim3(gbx1, 2), 256, 0, stream>>>(
        XBpk, 64, 64, 320, WP2, bb2, XBrow, 128, XBpk, 512, nullptr, nullptr, nullptr, N);

    // layer 3: agg(h2) -> XBpk cols 384..512; K=512 gemm (MT=2, NTB=8, grid.y=2) + fused pooling
    agg_pk<128, 512><<<ab, 256, 0, stream>>>(XBrow + 128, 256, XBpk, 384, rowstart, esrc, degf, N);
    gemm_fr<512, 512, 2, 8, 1><<<dim3(gbx2, 2), 256, 0, stream>>>(
        XBpk, 512, 0, 0, WP3, bb3, nullptr, 0, nullptr, 512, pmax, psum, batch, N);
    pool_final<<<(G * 256 + 255) / 256, 256, 0, stream>>>(pmax, psum, batch, pooled, G, N);

    // ---- dense head (fp32) ----
    gemm_lrelu<512, 512><<<dim3((G + 63) / 64, 8), 256, 0, stream>>>(
        pooled, 512, 0, 512, pooled, 512, 0, wd1, wd1 + 256 * 512, bd1, hid, 512, 0, G, 1);
    gemm_lrelu<512, 256><<<dim3((G + 63) / 64, 4), 256, 0, stream>>>(
        hid, 512, 0, 512, hid, 512, 0, wd2, wd2 + 256 * 256, bd2, (float*)d_out, 256, 0, G, 0);
}